// Round 4
// baseline (78.180 us; speedup 1.0000x reference)
//
#include <hip/hip_runtime.h>
#include <hip/hip_bf16.h>

#define NNODES 50000
#define NEDGES 200000
#define WCT_ROW 552                      // f16 units; 1104B row
#define WCT_BYTES (32 * WCT_ROW * 2)     // 35328
#define HROW 40                          // f16 units; 80B row
#define TILE_EDGES 64
#define NBLOCKS (NEDGES / TILE_EDGES)    // 3125

// workspace layout (bytes, all 16B-aligned)
#define AGG_OFF    0                     // f32[50000*32] = 6,400,000
#define CNT_OFF    6400000               // u32[50000]
#define ZERO_BYTES 6600000               // memset agg+counts
#define CUR_OFF    6600000               // u32[50000] cursor
#define PART_OFF   6800000               // u32[50176] block-local exclusive scan
#define BSUM_OFF   7000704               // u32[256] block sums
#define BSUM2_OFF  7001728               // u32[256] scanned block sums
#define EPERM_OFF  7002752               // u32[200000] sorted-edge permutation
#define WCT_OFF    7802752               // f16[32*552]

using f32x4 = __attribute__((ext_vector_type(4))) float;
using f16x2 = __attribute__((ext_vector_type(2))) _Float16;
using f16x4 = __attribute__((ext_vector_type(4))) _Float16;
using f16x8 = __attribute__((ext_vector_type(8))) _Float16;

__device__ __forceinline__ f16x2 pkrtz(float a, float b) {
    return __builtin_bit_cast(f16x2, __builtin_amdgcn_cvt_pkrtz(a, b));
}

__device__ __forceinline__ void gload_lds16(const void* g, void* l) {
    __builtin_amdgcn_global_load_lds(
        (const __attribute__((address_space(1))) unsigned int*)g,
        (__attribute__((address_space(3))) unsigned int*)l, 16, 0, 0);
}

// ---- fused: WcT prep (blocks 0..68) + dst histogram (blocks 69..850) ----
#define WCT_BLKS 69
__global__ void prep_hist_kernel(const float* __restrict__ W_edge,
                                 const float* __restrict__ b_edge,
                                 const int* __restrict__ dst,
                                 _Float16* __restrict__ wct,
                                 unsigned* __restrict__ counts) {
    int b = blockIdx.x;
    if (b < WCT_BLKS) {
        int gid = b * 256 + threadIdx.x;
        if (gid >= 32 * WCT_ROW) return;
        int n = gid / WCT_ROW;
        int c = gid - n * WCT_ROW;
        float v = 0.0f;
        if (c < 512)      v = W_edge[(c & 15) * 1024 + (c >> 4) * 32 + n];
        else if (c < 544) v = b_edge[(c - 512) * 32 + n];
        wct[gid] = (_Float16)v;
    } else {
        int gid = (b - WCT_BLKS) * 256 + threadIdx.x;
        if (gid < NEDGES) atomicAdd(&counts[dst[gid]], 1u);
    }
}

// ---- scan of counts[50000] -> cursor (exclusive prefix), 3 kernels ----
__global__ void scan1_kernel(const unsigned* __restrict__ counts,
                             unsigned* __restrict__ partial,
                             unsigned* __restrict__ bsum) {
    int t = threadIdx.x, gid = blockIdx.x * 256 + t;
    unsigned c = (gid < NNODES) ? counts[gid] : 0u;
    __shared__ unsigned s[256];
    s[t] = c; __syncthreads();
    #pragma unroll
    for (int off = 1; off < 256; off <<= 1) {
        unsigned v = (t >= off) ? s[t - off] : 0u;
        __syncthreads();
        s[t] += v;
        __syncthreads();
    }
    partial[gid] = s[t] - c;               // block-local exclusive
    if (t == 255) bsum[blockIdx.x] = s[t];
}

__global__ void scan2_kernel(unsigned* __restrict__ bsum,
                             unsigned* __restrict__ bsum2) {
    int t = threadIdx.x;
    unsigned c = (t < 196) ? bsum[t] : 0u;
    __shared__ unsigned s[256];
    s[t] = c; __syncthreads();
    #pragma unroll
    for (int off = 1; off < 256; off <<= 1) {
        unsigned v = (t >= off) ? s[t - off] : 0u;
        __syncthreads();
        s[t] += v;
        __syncthreads();
    }
    bsum2[t] = s[t] - c;                   // exclusive
}

__global__ void scan3_kernel(const unsigned* __restrict__ partial,
                             const unsigned* __restrict__ bsum2,
                             unsigned* __restrict__ cursor) {
    int gid = blockIdx.x * 256 + threadIdx.x;
    if (gid < NNODES) cursor[gid] = partial[gid] + bsum2[blockIdx.x];
}

__global__ void scatter_kernel(const int* __restrict__ dst,
                               unsigned* __restrict__ cursor,
                               unsigned* __restrict__ eperm) {
    int gid = blockIdx.x * 256 + threadIdx.x;
    if (gid >= NEDGES) return;
    unsigned pos = atomicAdd(&cursor[dst[gid]], 1u);
    eperm[pos] = (unsigned)gid;
}

// ---- main edge GEMM + segmented-reduce scatter ----
__global__ __launch_bounds__(256, 3) void edge_kernel(
    const float* __restrict__ feat, const float* __restrict__ efeat,
    const int* __restrict__ src, const int* __restrict__ dst,
    const unsigned* __restrict__ eperm,
    const _Float16* __restrict__ wct_g,
    float* __restrict__ agg) {

    __shared__ __align__(16) unsigned short wct_lds[32 * WCT_ROW]; // 35328 B
    __shared__ __align__(16) unsigned short h_lds[TILE_EDGES * HROW]; // 5120 B
    __shared__ __align__(16) float dtile[TILE_EDGES * 34];         // 8704 B
    __shared__ int dstx[66];  // dstx[1+r] = dst of sorted pos ebase+r; [0],[65] sentinels

    const int t = threadIdx.x;
    const int lane = t & 63;
    const int wave = t >> 6;
    const int ebase = blockIdx.x * TILE_EDGES;

    // Stage WcT global->LDS async (linear dest, 16B/lane)
    {
        const char* gsrc = (const char*)wct_g;
        char* lbase = (char*)wct_lds;
        #pragma unroll
        for (int c = 0; c < 9; ++c) {
            int chunk = wave + c * 4;
            if (chunk < 35) {
                int boff = (chunk << 10) + lane * 16;
                if (boff < WCT_BYTES) gload_lds16(gsrc + boff, lbase + boff);
            }
        }
    }

    // Stage sorted-run dst values + sentinels (consumed after 2nd barrier)
    if (t < 64)       dstx[t + 1] = dst[(int)eperm[ebase + t]];
    else if (t == 64) dstx[0]  = (ebase > 0)          ? dst[(int)eperm[ebase - 1]]  : -1;
    else if (t == 65) dstx[65] = (ebase + 64 < NEDGES) ? dst[(int)eperm[ebase + 64]] : -1;

    // Stage gathered h (f32 -> f16) for the 64 permuted edges
    {
        int et = t >> 2, p = t & 3;
        int se = src[(int)eperm[ebase + et]];
        const float* fp = feat + se * 32 + p * 8;
        float4 a = *(const float4*)fp;
        float4 b = *(const float4*)(fp + 4);
        uint4 hp;
        hp.x = __builtin_bit_cast(unsigned int, pkrtz(a.x, a.y));
        hp.y = __builtin_bit_cast(unsigned int, pkrtz(a.z, a.w));
        hp.z = __builtin_bit_cast(unsigned int, pkrtz(b.x, b.y));
        hp.w = __builtin_bit_cast(unsigned int, pkrtz(b.z, b.w));
        *(uint4*)(void*)(h_lds + et * HROW + p * 8) = hp;
    }

    const int r16 = lane & 15;
    const int g   = lane >> 4;
    const int wbase = wave * 16;

    // ef fragment for this lane's edge (permuted row gather, 64B aligned)
    const int ep_lane = (int)eperm[ebase + wbase + r16];
    const float* efp = efeat + ep_lane * 16 + (g & 1) * 8;
    float4 e0 = *(const float4*)efp;
    float4 e1 = *(const float4*)(efp + 4);
    f16x2 ef2[4] = { pkrtz(e0.x, e0.y), pkrtz(e0.z, e0.w),
                     pkrtz(e1.x, e1.y), pkrtz(e1.z, e1.w) };

    __syncthreads();   // drains global_load_lds + ds_writes

    // h row -> regs; per-s broadcast half2 of h[2s + (g>>1)]
    unsigned int hbc[16];
    {
        const uint4* hrow = (const uint4*)(void*)(h_lds + (wbase + r16) * HROW);
        unsigned int hw[16];
        #pragma unroll
        for (int q = 0; q < 4; ++q) {
            uint4 v = hrow[q];
            hw[q*4+0] = v.x; hw[q*4+1] = v.y; hw[q*4+2] = v.z; hw[q*4+3] = v.w;
        }
        const bool hi = (g >> 1) & 1;
        #pragma unroll
        for (int s = 0; s < 16; ++s) {
            unsigned int x = hi ? (hw[s] >> 16) : (hw[s] & 0xffffu);
            hbc[s] = x | (x << 16);
        }
    }

    const _Float16* brow0 = (const _Float16*)wct_lds + r16 * WCT_ROW;
    const _Float16* brow1 = (const _Float16*)wct_lds + (16 + r16) * WCT_ROW;

    f32x4 acc0 = {0.f, 0.f, 0.f, 0.f};
    f32x4 acc1 = {0.f, 0.f, 0.f, 0.f};

    #pragma unroll
    for (int s = 0; s < 16; ++s) {
        const int koff = s * 32 + g * 8;
        f16x8 b0 = *(const f16x8*)(brow0 + koff);
        f16x8 b1 = *(const f16x8*)(brow1 + koff);
        f16x2 hb = __builtin_bit_cast(f16x2, hbc[s]);
        f16x2 p0 = hb * ef2[0], p1 = hb * ef2[1], p2 = hb * ef2[2], p3 = hb * ef2[3];
        f16x4 lo  = __builtin_shufflevector(p0, p1, 0, 1, 2, 3);
        f16x4 hi4 = __builtin_shufflevector(p2, p3, 0, 1, 2, 3);
        f16x8 af  = __builtin_shufflevector(lo, hi4, 0, 1, 2, 3, 4, 5, 6, 7);
        acc0 = __builtin_amdgcn_mfma_f32_16x16x32_f16(af, b0, acc0, 0, 0, 0);
        acc1 = __builtin_amdgcn_mfma_f32_16x16x32_f16(af, b1, acc1, 0, 0, 0);
    }
    {   // bias-extension k-step: X[e, 512+i] = h[i]
        const int koff = 512 + g * 8;
        f16x8 b0 = *(const f16x8*)(brow0 + koff);
        f16x8 b1 = *(const f16x8*)(brow1 + koff);
        f16x8 af = *(const f16x8*)(void*)((const _Float16*)h_lds + (wbase + r16) * HROW + g * 8);
        acc0 = __builtin_amdgcn_mfma_f32_16x16x32_f16(af, b0, acc0, 0, 0, 0);
        acc1 = __builtin_amdgcn_mfma_f32_16x16x32_f16(af, b1, acc1, 0, 0, 0);
    }

    // D (m89): row = g*4+r (edge), col = r16 -> block tile [64][34]
    {
        const int browD = wbase + g * 4;
        #pragma unroll
        for (int r = 0; r < 4; ++r) {
            dtile[(browD + r) * 34 + r16]      = acc0[r];
            dtile[(browD + r) * 34 + 16 + r16] = acc1[r];
        }
    }
    __syncthreads();

    // Segmented reduce over sorted dst runs: wave 0, lane = col + 32*half
    if (t < 64) {
        const int col = t & 31;
        const int h0  = (t >> 5) * 32;          // rows [h0, h0+32)
        float cur  = dtile[h0 * 34 + col];
        int   dcur = dstx[h0 + 1];
        bool  startb = (dstx[h0] == dcur);      // run continues from before
        #pragma unroll 4
        for (int rr = 1; rr < 32; ++rr) {
            int   d = dstx[h0 + rr + 1];
            float v = dtile[(h0 + rr) * 34 + col];
            if (d == dcur) {
                cur += v;
            } else {
                if (startb) atomicAdd(&agg[dcur * 32 + col], cur);
                else        agg[dcur * 32 + col] = cur;   // complete run: sole writer
                cur = v; dcur = d; startb = false;
            }
        }
        bool endb = (dstx[h0 + 33] == dcur);
        if (startb || endb) atomicAdd(&agg[dcur * 32 + col], cur);
        else                agg[dcur * 32 + col] = cur;
    }
}

__global__ void finalize_kernel(const float* __restrict__ agg,
                                const unsigned* __restrict__ counts,
                                const float* __restrict__ bias,
                                float* __restrict__ out) {
    int gid = blockIdx.x * 256 + threadIdx.x;
    if (gid >= NNODES * 8) return;
    int node = gid >> 3;
    int c = (gid & 7) * 4;
    float inv = 1.0f / fmaxf((float)counts[node], 1.0f);
    float4 a = *(const float4*)(agg + node * 32 + c);
    float4 b = *(const float4*)(bias + c);
    float4 o = { a.x * inv + b.x, a.y * inv + b.y, a.z * inv + b.z, a.w * inv + b.w };
    *(float4*)(out + node * 32 + c) = o;
}

extern "C" void kernel_launch(void* const* d_in, const int* in_sizes, int n_in,
                              void* d_out, int out_size, void* d_ws, size_t ws_size,
                              hipStream_t stream) {
    const float* feat   = (const float*)d_in[0];
    const float* efeat  = (const float*)d_in[1];
    const int*   src    = (const int*)d_in[2];
    const int*   dst    = (const int*)d_in[3];
    const float* W_edge = (const float*)d_in[4];
    const float* b_edge = (const float*)d_in[5];
    const float* bias   = (const float*)d_in[6];

    char* ws = (char*)d_ws;
    float*    agg    = (float*)(ws + AGG_OFF);
    unsigned* counts = (unsigned*)(ws + CNT_OFF);
    unsigned* cursor = (unsigned*)(ws + CUR_OFF);
    unsigned* part   = (unsigned*)(ws + PART_OFF);
    unsigned* bsum   = (unsigned*)(ws + BSUM_OFF);
    unsigned* bsum2  = (unsigned*)(ws + BSUM2_OFF);
    unsigned* eperm  = (unsigned*)(ws + EPERM_OFF);
    _Float16* wct    = (_Float16*)(ws + WCT_OFF);
    float*    out    = (float*)d_out;

    (void)hipMemsetAsync(d_ws, 0, ZERO_BYTES, stream);
    prep_hist_kernel<<<WCT_BLKS + (NEDGES + 255) / 256, 256, 0, stream>>>(
        W_edge, b_edge, dst, wct, counts);
    scan1_kernel<<<196, 256, 0, stream>>>(counts, part, bsum);
    scan2_kernel<<<1, 256, 0, stream>>>(bsum, bsum2);
    scan3_kernel<<<196, 256, 0, stream>>>(part, bsum2, cursor);
    scatter_kernel<<<(NEDGES + 255) / 256, 256, 0, stream>>>(dst, cursor, eperm);
    edge_kernel<<<NBLOCKS, 256, 0, stream>>>(feat, efeat, src, dst, eperm, wct, agg);
    finalize_kernel<<<(NNODES * 8 + 255) / 256, 256, 0, stream>>>(agg, counts, bias, out);
}

// Round 6
// 72.017 us; speedup vs baseline: 1.0856x; 1.0856x over previous
//
#include <hip/hip_runtime.h>
#include <hip/hip_bf16.h>
#include <hip/hip_fp16.h>

#define NNODES 50000
#define NEDGES 200000
#define WCT_ROW 552                      // f16 units; 1104B row
#define WCT_BYTES (32 * WCT_ROW * 2)     // 35328
#define HROW 40                          // f16 units; 80B row
#define TILE_EDGES 64
#define NBLOCKS (NEDGES / TILE_EDGES)    // 3125
#define DROW 36                          // dtile row stride (floats)

// workspace layout (bytes)
#define AGG_OFF  0                       // f16[50000*32] = 3,200,000
#define DEG_OFF  3200000                 // f32[50000]    =   200,000
#define ZERO_F4  212500                  // 3,400,000 bytes / 16
#define WCT_OFF  3400000                 // f16[32*552], 16B-aligned

using f32x4 = __attribute__((ext_vector_type(4))) float;
using f16x2 = __attribute__((ext_vector_type(2))) _Float16;
using f16x4 = __attribute__((ext_vector_type(4))) _Float16;
using f16x8 = __attribute__((ext_vector_type(8))) _Float16;

__device__ __forceinline__ f16x2 pkrtz(float a, float b) {
    return __builtin_bit_cast(f16x2, __builtin_amdgcn_cvt_pkrtz(a, b));
}

__device__ __forceinline__ void gload_lds16(const void* g, void* l) {
    __builtin_amdgcn_global_load_lds(
        (const __attribute__((address_space(1))) unsigned int*)g,
        (__attribute__((address_space(3))) unsigned int*)l, 16, 0, 0);
}

// ---- fused: WcT prep (blocks 0..68) + zero agg/deg (blocks 69..) ----
#define WCT_BLKS 69
__global__ void prep_zero_kernel(const float* __restrict__ W_edge,
                                 const float* __restrict__ b_edge,
                                 _Float16* __restrict__ wct,
                                 f32x4* __restrict__ zero_base) {
    int b = blockIdx.x;
    if (b < WCT_BLKS) {
        int gid = b * 256 + threadIdx.x;
        if (gid >= 32 * WCT_ROW) return;
        int n = gid / WCT_ROW;
        int c = gid - n * WCT_ROW;
        float v = 0.0f;
        if (c < 512)      v = W_edge[(c & 15) * 1024 + (c >> 4) * 32 + n];
        else if (c < 544) v = b_edge[(c - 512) * 32 + n];
        wct[gid] = (_Float16)v;
    } else {
        int idx = (b - WCT_BLKS) * 256 + threadIdx.x;
        if (idx < ZERO_F4) zero_base[idx] = (f32x4){0.f, 0.f, 0.f, 0.f};
    }
}

// ---- main edge GEMM + transposed pk-f16 atomic scatter ----
__global__ __launch_bounds__(256, 3) void edge_kernel(
    const float* __restrict__ feat, const float* __restrict__ efeat,
    const int* __restrict__ src, const int* __restrict__ dst,
    const _Float16* __restrict__ wct_g,
    __half2* __restrict__ aggh, float* __restrict__ deg) {

    __shared__ __align__(16) unsigned short wct_lds[32 * WCT_ROW]; // 35328 B
    __shared__ __align__(16) unsigned short h_lds[TILE_EDGES * HROW]; // 5120 B
    __shared__ __align__(16) float dtile[TILE_EDGES * DROW];       // 9216 B
    __shared__ int dst_lds[TILE_EDGES];

    const int t = threadIdx.x;
    const int lane = t & 63;
    const int wave = t >> 6;
    const int ebase = blockIdx.x * TILE_EDGES;

    // Stage WcT global->LDS async (linear dest, 16B/lane)
    {
        const char* gsrc = (const char*)wct_g;
        char* lbase = (char*)wct_lds;
        #pragma unroll
        for (int c = 0; c < 9; ++c) {
            int chunk = wave + c * 4;
            if (chunk < 35) {
                int boff = (chunk << 10) + lane * 16;
                if (boff < WCT_BYTES) gload_lds16(gsrc + boff, lbase + boff);
            }
        }
    }

    // Stage gathered h (f32 -> f16) + dst for 64 edges
    {
        int et = t >> 2, p = t & 3;
        int se = src[ebase + et];
        const float* fp = feat + se * 32 + p * 8;
        float4 a = *(const float4*)fp;
        float4 b = *(const float4*)(fp + 4);
        uint4 hp;
        hp.x = __builtin_bit_cast(unsigned int, pkrtz(a.x, a.y));
        hp.y = __builtin_bit_cast(unsigned int, pkrtz(a.z, a.w));
        hp.z = __builtin_bit_cast(unsigned int, pkrtz(b.x, b.y));
        hp.w = __builtin_bit_cast(unsigned int, pkrtz(b.z, b.w));
        *(uint4*)(void*)(h_lds + et * HROW + p * 8) = hp;
        if (t < TILE_EDGES) dst_lds[t] = dst[ebase + t];
    }

    const int r16 = lane & 15;
    const int g   = lane >> 4;
    const int wbase = wave * 16;
    const int eg = ebase + wbase + r16;

    // ef fragment (independent of LDS; overlaps staging latency)
    const float* efp = efeat + eg * 16 + (g & 1) * 8;
    float4 e0 = *(const float4*)efp;
    float4 e1 = *(const float4*)(efp + 4);
    f16x2 ef2[4] = { pkrtz(e0.x, e0.y), pkrtz(e0.z, e0.w),
                     pkrtz(e1.x, e1.y), pkrtz(e1.z, e1.w) };

    __syncthreads();   // drains global_load_lds + ds_writes

    // h row -> regs; per-s broadcast half2 of h[2s + (g>>1)]
    unsigned int hbc[16];
    {
        const uint4* hrow = (const uint4*)(void*)(h_lds + (wbase + r16) * HROW);
        unsigned int hw[16];
        #pragma unroll
        for (int q = 0; q < 4; ++q) {
            uint4 v = hrow[q];
            hw[q*4+0] = v.x; hw[q*4+1] = v.y; hw[q*4+2] = v.z; hw[q*4+3] = v.w;
        }
        const bool hi = (g >> 1) & 1;
        #pragma unroll
        for (int s = 0; s < 16; ++s) {
            unsigned int x = hi ? (hw[s] >> 16) : (hw[s] & 0xffffu);
            hbc[s] = x | (x << 16);
        }
    }

    const _Float16* brow0 = (const _Float16*)wct_lds + r16 * WCT_ROW;
    const _Float16* brow1 = (const _Float16*)wct_lds + (16 + r16) * WCT_ROW;

    f32x4 acc0 = {0.f, 0.f, 0.f, 0.f};
    f32x4 acc1 = {0.f, 0.f, 0.f, 0.f};

    // X[e,c] = h[i]*ef[kk], c = 32s + 8g + j  =>  i = 2s+(g>>1), kk = (g&1)*8+j
    #pragma unroll
    for (int s = 0; s < 16; ++s) {
        const int koff = s * 32 + g * 8;
        f16x8 b0 = *(const f16x8*)(brow0 + koff);
        f16x8 b1 = *(const f16x8*)(brow1 + koff);
        f16x2 hb = __builtin_bit_cast(f16x2, hbc[s]);
        f16x2 p0 = hb * ef2[0], p1 = hb * ef2[1], p2 = hb * ef2[2], p3 = hb * ef2[3];
        f16x4 lo  = __builtin_shufflevector(p0, p1, 0, 1, 2, 3);
        f16x4 hi4 = __builtin_shufflevector(p2, p3, 0, 1, 2, 3);
        f16x8 af  = __builtin_shufflevector(lo, hi4, 0, 1, 2, 3, 4, 5, 6, 7);
        acc0 = __builtin_amdgcn_mfma_f32_16x16x32_f16(af, b0, acc0, 0, 0, 0);
        acc1 = __builtin_amdgcn_mfma_f32_16x16x32_f16(af, b1, acc1, 0, 0, 0);
    }
    {   // bias-extension k-step: X[e, 512+i] = h[i]
        const int koff = 512 + g * 8;
        f16x8 b0 = *(const f16x8*)(brow0 + koff);
        f16x8 b1 = *(const f16x8*)(brow1 + koff);
        f16x8 af = *(const f16x8*)(void*)((const _Float16*)h_lds + (wbase + r16) * HROW + g * 8);
        acc0 = __builtin_amdgcn_mfma_f32_16x16x32_f16(af, b0, acc0, 0, 0, 0);
        acc1 = __builtin_amdgcn_mfma_f32_16x16x32_f16(af, b1, acc1, 0, 0, 0);
    }

    // D (m89): row = g*4+r (edge within wave tile), col = r16 -> dtile[64][36]
    {
        const int browD = wbase + g * 4;
        #pragma unroll
        for (int r = 0; r < 4; ++r) {
            dtile[(browD + r) * DROW + r16]      = acc0[r];
            dtile[(browD + r) * DROW + 16 + r16] = acc1[r];
        }
    }
    __syncthreads();

    // Transposed scatter: thread t -> edge et, 8 consecutive channels,
    // 4 packed-f16 atomics (global_atomic_pk_add_f16 via unsafeAtomicAdd)
    {
        const int et = t >> 2, q = t & 3;
        const int dn = dst_lds[et];
        const float* drow = dtile + et * DROW + q * 8;
        f32x4 v0 = *(const f32x4*)(drow);
        f32x4 v1 = *(const f32x4*)(drow + 4);
        __half2* base = aggh + dn * 16 + q * 4;
        unsafeAtomicAdd(base + 0, __builtin_bit_cast(__half2, pkrtz(v0[0], v0[1])));
        unsafeAtomicAdd(base + 1, __builtin_bit_cast(__half2, pkrtz(v0[2], v0[3])));
        unsafeAtomicAdd(base + 2, __builtin_bit_cast(__half2, pkrtz(v1[0], v1[1])));
        unsafeAtomicAdd(base + 3, __builtin_bit_cast(__half2, pkrtz(v1[2], v1[3])));
        if (q == 0) atomicAdd(deg + dn, 1.0f);
    }
}

__global__ void finalize_kernel(const __half2* __restrict__ aggh,
                                const float* __restrict__ deg,
                                const float* __restrict__ bias,
                                float* __restrict__ out) {
    int gid = blockIdx.x * 256 + threadIdx.x;
    if (gid >= NNODES * 4) return;
    int node = gid >> 2;
    int c = (gid & 3) * 8;
    float inv = 1.0f / fmaxf(deg[node], 1.0f);
    const __half2* ap = aggh + node * 16 + (gid & 3) * 4;
    float4 b0 = *(const float4*)(bias + c);
    float4 b1 = *(const float4*)(bias + c + 4);
    float2 a0 = __half22float2(ap[0]);
    float2 a1 = __half22float2(ap[1]);
    float2 a2 = __half22float2(ap[2]);
    float2 a3 = __half22float2(ap[3]);
    float4 o0 = { a0.x * inv + b0.x, a0.y * inv + b0.y, a1.x * inv + b0.z, a1.y * inv + b0.w };
    float4 o1 = { a2.x * inv + b1.x, a2.y * inv + b1.y, a3.x * inv + b1.z, a3.y * inv + b1.w };
    *(float4*)(out + node * 32 + c)     = o0;
    *(float4*)(out + node * 32 + c + 4) = o1;
}

extern "C" void kernel_launch(void* const* d_in, const int* in_sizes, int n_in,
                              void* d_out, int out_size, void* d_ws, size_t ws_size,
                              hipStream_t stream) {
    const float* feat   = (const float*)d_in[0];
    const float* efeat  = (const float*)d_in[1];
    const int*   src    = (const int*)d_in[2];
    const int*   dst    = (const int*)d_in[3];
    const float* W_edge = (const float*)d_in[4];
    const float* b_edge = (const float*)d_in[5];
    const float* bias   = (const float*)d_in[6];

    char* ws = (char*)d_ws;
    __half2*  aggh = (__half2*)(ws + AGG_OFF);
    float*    deg  = (float*)(ws + DEG_OFF);
    _Float16* wct  = (_Float16*)(ws + WCT_OFF);
    float*    out  = (float*)d_out;

    const int zero_blocks = (ZERO_F4 + 255) / 256;   // 831
    prep_zero_kernel<<<WCT_BLKS + zero_blocks, 256, 0, stream>>>(
        W_edge, b_edge, wct, (f32x4*)ws);
    edge_kernel<<<NBLOCKS, 256, 0, stream>>>(feat, efeat, src, dst, wct, aggh, deg);
    finalize_kernel<<<(NNODES * 4 + 255) / 256, 256, 0, stream>>>(aggh, deg, bias, out);
}

// Round 7
// 54.539 us; speedup vs baseline: 1.4335x; 1.3205x over previous
//
#include <hip/hip_runtime.h>
#include <hip/hip_bf16.h>

#define NNODES 50000
#define NEDGES 200000
#define NTILES 3125                      // 64-edge tiles
#define WCT_ROW 552                      // f16 units; 1104B row
#define WCT_BYTES (32 * WCT_ROW * 2)     // 35328
#define HROW 40                          // f16 units; 80B row
#define TILE_EDGES 64
#define NBLOCKS ((NTILES + 1) / 2)       // 1563 blocks x 2 tiles

// workspace layout (bytes)
#define AGG_OFF  0                       // f32[50000*32] = 6,400,000
#define DEG_OFF  6400000                 // f32[50000]    =   200,000
#define ZERO_F4  412500                  // 6,600,000 / 16
#define WCT_OFF  6600000                 // f16[32*552], 16B-aligned

using f32x4 = __attribute__((ext_vector_type(4))) float;
using f16x2 = __attribute__((ext_vector_type(2))) _Float16;
using f16x4 = __attribute__((ext_vector_type(4))) _Float16;
using f16x8 = __attribute__((ext_vector_type(8))) _Float16;

__device__ __forceinline__ f16x2 pkrtz(float a, float b) {
    return __builtin_bit_cast(f16x2, __builtin_amdgcn_cvt_pkrtz(a, b));
}

__device__ __forceinline__ void gload_lds16(const void* g, void* l) {
    __builtin_amdgcn_global_load_lds(
        (const __attribute__((address_space(1))) unsigned int*)g,
        (__attribute__((address_space(3))) unsigned int*)l, 16, 0, 0);
}

// ---- fused: WcT prep (blocks 0..68) + zero agg/deg (blocks 69..) ----
#define WCT_BLKS 69
__global__ void prep_zero_kernel(const float* __restrict__ W_edge,
                                 const float* __restrict__ b_edge,
                                 _Float16* __restrict__ wct,
                                 f32x4* __restrict__ zero_base) {
    int b = blockIdx.x;
    if (b < WCT_BLKS) {
        int gid = b * 256 + threadIdx.x;
        if (gid >= 32 * WCT_ROW) return;
        int n = gid / WCT_ROW;
        int c = gid - n * WCT_ROW;
        float v = 0.0f;
        if (c < 512)      v = W_edge[(c & 15) * 1024 + (c >> 4) * 32 + n];
        else if (c < 544) v = b_edge[(c - 512) * 32 + n];
        wct[gid] = (_Float16)v;
    } else {
        int idx = (b - WCT_BLKS) * 256 + threadIdx.x;
        if (idx < ZERO_F4) zero_base[idx] = (f32x4){0.f, 0.f, 0.f, 0.f};
    }
}

// ---- main edge GEMM + f32 atomic scatter; 512 thr = 2 tiles sharing wct ----
__global__ __launch_bounds__(512, 6) void edge_kernel(
    const float* __restrict__ feat, const float* __restrict__ efeat,
    const int* __restrict__ src, const int* __restrict__ dst,
    const _Float16* __restrict__ wct_g,
    float* __restrict__ agg, float* __restrict__ deg) {

    __shared__ __align__(16) unsigned short wct_lds[32 * WCT_ROW];     // 35328 B
    __shared__ __align__(16) unsigned short h_lds[2][TILE_EDGES * HROW]; // 10240 B
    __shared__ int dst_lds[2][TILE_EDGES];                             // 512 B

    const int t    = threadIdx.x;
    const int lane = t & 63;
    const int wave = t >> 6;      // 0..7
    const int sb   = wave >> 2;   // sub-block (tile) 0/1
    const int wsub = wave & 3;    // wave within sub-block
    const int tl   = t & 255;     // thread within sub-block

    const int tile  = blockIdx.x * 2 + sb;
    const bool valid = (tile < NTILES);
    const int ebase = tile * TILE_EDGES;

    // Stage WcT global->LDS async, all 8 waves (linear dest, 16B/lane)
    {
        const char* gsrc = (const char*)wct_g;
        char* lbase = (char*)wct_lds;
        #pragma unroll
        for (int c = 0; c < 5; ++c) {
            int chunk = wave + c * 8;            // wave-uniform
            if (chunk < 35) {
                int boff = (chunk << 10) + lane * 16;
                if (boff < WCT_BYTES) gload_lds16(gsrc + boff, lbase + boff);
            }
        }
    }

    const int r16 = lane & 15;
    const int g   = lane >> 4;
    const int wbase = wsub * 16;

    f16x2 ef2[4];
    if (valid) {
        // Stage gathered h (f32 -> f16) + dst for this sub-block's 64 edges
        {
            int et = tl >> 2, p = tl & 3;
            int se = src[ebase + et];
            const float* fp = feat + se * 32 + p * 8;
            float4 a = *(const float4*)fp;
            float4 b = *(const float4*)(fp + 4);
            uint4 hp;
            hp.x = __builtin_bit_cast(unsigned int, pkrtz(a.x, a.y));
            hp.y = __builtin_bit_cast(unsigned int, pkrtz(a.z, a.w));
            hp.z = __builtin_bit_cast(unsigned int, pkrtz(b.x, b.y));
            hp.w = __builtin_bit_cast(unsigned int, pkrtz(b.z, b.w));
            *(uint4*)(void*)(&h_lds[sb][et * HROW + p * 8]) = hp;
            if (tl < TILE_EDGES) dst_lds[sb][tl] = dst[ebase + tl];
        }
        // ef fragment (independent of LDS; overlaps staging latency)
        const int eg = ebase + wbase + r16;
        const float* efp = efeat + eg * 16 + (g & 1) * 8;
        float4 e0 = *(const float4*)efp;
        float4 e1 = *(const float4*)(efp + 4);
        ef2[0] = pkrtz(e0.x, e0.y); ef2[1] = pkrtz(e0.z, e0.w);
        ef2[2] = pkrtz(e1.x, e1.y); ef2[3] = pkrtz(e1.z, e1.w);
    }

    __syncthreads();   // drains global_load_lds + ds_writes (all 512 threads)

    if (!valid) return;

    // h row -> regs; per-s broadcast half2 of h[2s + (g>>1)]
    unsigned int hbc[16];
    {
        const uint4* hrow = (const uint4*)(void*)(&h_lds[sb][(wbase + r16) * HROW]);
        unsigned int hw[16];
        #pragma unroll
        for (int q = 0; q < 4; ++q) {
            uint4 v = hrow[q];
            hw[q*4+0] = v.x; hw[q*4+1] = v.y; hw[q*4+2] = v.z; hw[q*4+3] = v.w;
        }
        const bool hi = (g >> 1) & 1;
        #pragma unroll
        for (int s = 0; s < 16; ++s) {
            unsigned int x = hi ? (hw[s] >> 16) : (hw[s] & 0xffffu);
            hbc[s] = x | (x << 16);
        }
    }

    const _Float16* brow0 = (const _Float16*)wct_lds + r16 * WCT_ROW;
    const _Float16* brow1 = (const _Float16*)wct_lds + (16 + r16) * WCT_ROW;

    f32x4 acc0 = {0.f, 0.f, 0.f, 0.f};
    f32x4 acc1 = {0.f, 0.f, 0.f, 0.f};

    // X[e,c] = h[i]*ef[kk], c = 32s + 8g + j  =>  i = 2s+(g>>1), kk = (g&1)*8+j
    #pragma unroll
    for (int s = 0; s < 16; ++s) {
        const int koff = s * 32 + g * 8;
        f16x8 b0 = *(const f16x8*)(brow0 + koff);
        f16x8 b1 = *(const f16x8*)(brow1 + koff);
        f16x2 hb = __builtin_bit_cast(f16x2, hbc[s]);
        f16x2 p0 = hb * ef2[0], p1 = hb * ef2[1], p2 = hb * ef2[2], p3 = hb * ef2[3];
        f16x4 lo  = __builtin_shufflevector(p0, p1, 0, 1, 2, 3);
        f16x4 hi4 = __builtin_shufflevector(p2, p3, 0, 1, 2, 3);
        f16x8 af  = __builtin_shufflevector(lo, hi4, 0, 1, 2, 3, 4, 5, 6, 7);
        acc0 = __builtin_amdgcn_mfma_f32_16x16x32_f16(af, b0, acc0, 0, 0, 0);
        acc1 = __builtin_amdgcn_mfma_f32_16x16x32_f16(af, b1, acc1, 0, 0, 0);
    }
    {   // bias-extension k-step: X[e, 512+i] = h[i]
        const int koff = 512 + g * 8;
        f16x8 b0 = *(const f16x8*)(brow0 + koff);
        f16x8 b1 = *(const f16x8*)(brow1 + koff);
        f16x8 af = *(const f16x8*)(void*)((const _Float16*)&h_lds[sb][0] + (wbase + r16) * HROW + g * 8);
        acc0 = __builtin_amdgcn_mfma_f32_16x16x32_f16(af, b0, acc0, 0, 0, 0);
        acc1 = __builtin_amdgcn_mfma_f32_16x16x32_f16(af, b1, acc1, 0, 0, 0);
    }

    // D (m89): row = g*4+r (edge within wave tile), col = r16; direct f32 atomics
    #pragma unroll
    for (int r = 0; r < 4; ++r) {
        int dn = dst_lds[sb][wbase + g * 4 + r];
        atomicAdd(&agg[dn * 32 + r16], acc0[r]);
        atomicAdd(&agg[dn * 32 + 16 + r16], acc1[r]);
    }
    if (lane < 16) atomicAdd(&deg[dst_lds[sb][wbase + lane]], 1.0f);
}

__global__ void finalize_kernel(const float* __restrict__ agg,
                                const float* __restrict__ deg,
                                const float* __restrict__ bias,
                                float* __restrict__ out) {
    int gid = blockIdx.x * 256 + threadIdx.x;
    if (gid >= NNODES * 8) return;
    int node = gid >> 3;
    int c = (gid & 7) * 4;
    float inv = 1.0f / fmaxf(deg[node], 1.0f);
    float4 a = *(const float4*)(agg + node * 32 + c);
    float4 b = *(const float4*)(bias + c);
    float4 o = { a.x * inv + b.x, a.y * inv + b.y, a.z * inv + b.z, a.w * inv + b.w };
    *(float4*)(out + node * 32 + c) = o;
}

extern "C" void kernel_launch(void* const* d_in, const int* in_sizes, int n_in,
                              void* d_out, int out_size, void* d_ws, size_t ws_size,
                              hipStream_t stream) {
    const float* feat   = (const float*)d_in[0];
    const float* efeat  = (const float*)d_in[1];
    const int*   src    = (const int*)d_in[2];
    const int*   dst    = (const int*)d_in[3];
    const float* W_edge = (const float*)d_in[4];
    const float* b_edge = (const float*)d_in[5];
    const float* bias   = (const float*)d_in[6];

    char* ws = (char*)d_ws;
    float*    agg = (float*)(ws + AGG_OFF);
    float*    deg = (float*)(ws + DEG_OFF);
    _Float16* wct = (_Float16*)(ws + WCT_OFF);
    float*    out = (float*)d_out;

    const int zero_blocks = (ZERO_F4 + 255) / 256;   // 1612
    prep_zero_kernel<<<WCT_BLKS + zero_blocks, 256, 0, stream>>>(
        W_edge, b_edge, wct, (f32x4*)ws);
    edge_kernel<<<NBLOCKS, 512, 0, stream>>>(feat, efeat, src, dst, wct, agg, deg);
    finalize_kernel<<<(NNODES * 8 + 255) / 256, 256, 0, stream>>>(agg, deg, bias, out);
}

// Round 8
// 48.207 us; speedup vs baseline: 1.6218x; 1.1313x over previous
//
#include <hip/hip_runtime.h>
#include <hip/hip_bf16.h>

#define NNODES 50000
#define NEDGES 200000
#define WCT_ROW 552                      // f16 units; 1104B row
#define WCT_BYTES (32 * WCT_ROW * 2)     // 35328
#define HROW 40                          // f16 units; 80B row
#define TILE_EDGES 64
#define NTILES (NEDGES / TILE_EDGES)     // 3125 GEMM blocks
#define CHAIN_BLKS ((NEDGES + 255) / 256) // 782
#define DROW 36                          // dtile row stride (floats)

// workspace layout (bytes, 16B-aligned)
#define MSG_OFF   0                      // f32[200000*32] = 25,600,000
#define HEAD_OFF  25600000               // u32[50000]
#define NEXT_OFF  25800000               // u32[200000]
#define WCT_OFF   26600000               // f16[32*552]

using f32x4 = __attribute__((ext_vector_type(4))) float;
using f16x2 = __attribute__((ext_vector_type(2))) _Float16;
using f16x4 = __attribute__((ext_vector_type(4))) _Float16;
using f16x8 = __attribute__((ext_vector_type(8))) _Float16;

__device__ __forceinline__ f16x2 pkrtz(float a, float b) {
    return __builtin_bit_cast(f16x2, __builtin_amdgcn_cvt_pkrtz(a, b));
}

__device__ __forceinline__ void gload_lds16(const void* g, void* l) {
    __builtin_amdgcn_global_load_lds(
        (const __attribute__((address_space(1))) unsigned int*)g,
        (__attribute__((address_space(3))) unsigned int*)l, 16, 0, 0);
}

// ---- D1: wct build (blocks 0..68) + head init (blocks 69..264) ----
#define WCT_BLKS 69
__global__ void init_kernel(const float* __restrict__ W_edge,
                            const float* __restrict__ b_edge,
                            _Float16* __restrict__ wct,
                            unsigned* __restrict__ head) {
    int b = blockIdx.x;
    if (b < WCT_BLKS) {
        int gid = b * 256 + threadIdx.x;
        if (gid >= 32 * WCT_ROW) return;
        int n = gid / WCT_ROW;
        int c = gid - n * WCT_ROW;
        float v = 0.0f;
        if (c < 512)      v = W_edge[(c & 15) * 1024 + (c >> 4) * 32 + n];
        else if (c < 544) v = b_edge[(c - 512) * 32 + n];
        wct[gid] = (_Float16)v;
    } else {
        int gid = (b - WCT_BLKS) * 256 + threadIdx.x;
        if (gid < NNODES) head[gid] = 0xFFFFFFFFu;
    }
}

// ---- D2: GEMM blocks (0..3124) write msg; chain blocks (3125..) scatter ----
__global__ __launch_bounds__(256, 3) void work_kernel(
    const float* __restrict__ feat, const float* __restrict__ efeat,
    const int* __restrict__ src, const int* __restrict__ dst,
    const _Float16* __restrict__ wct_g,
    float* __restrict__ msg, unsigned* __restrict__ head,
    unsigned* __restrict__ next) {

    __shared__ __align__(16) unsigned short wct_lds[32 * WCT_ROW]; // 35328 B
    __shared__ __align__(16) unsigned short h_lds[TILE_EDGES * HROW]; // 5120 B
    __shared__ __align__(16) float dtile[TILE_EDGES * DROW];       // 9216 B

    const int t = threadIdx.x;

    if (blockIdx.x >= NTILES) {
        // chain-scatter: per-dst linked list via atomicExch (200K atomics)
        int e = (blockIdx.x - NTILES) * 256 + t;
        if (e < NEDGES)
            next[e] = atomicExch(&head[dst[e]], (unsigned)e);
        return;
    }

    const int lane = t & 63;
    const int wave = t >> 6;
    const int ebase = blockIdx.x * TILE_EDGES;

    // Stage WcT global->LDS async (linear dest, 16B/lane)
    {
        const char* gsrc = (const char*)wct_g;
        char* lbase = (char*)wct_lds;
        #pragma unroll
        for (int c = 0; c < 9; ++c) {
            int chunk = wave + c * 4;
            if (chunk < 35) {
                int boff = (chunk << 10) + lane * 16;
                if (boff < WCT_BYTES) gload_lds16(gsrc + boff, lbase + boff);
            }
        }
    }

    // Stage gathered h (f32 -> f16) for 64 edges
    {
        int et = t >> 2, p = t & 3;
        int se = src[ebase + et];
        const float* fp = feat + se * 32 + p * 8;
        float4 a = *(const float4*)fp;
        float4 b = *(const float4*)(fp + 4);
        uint4 hp;
        hp.x = __builtin_bit_cast(unsigned int, pkrtz(a.x, a.y));
        hp.y = __builtin_bit_cast(unsigned int, pkrtz(a.z, a.w));
        hp.z = __builtin_bit_cast(unsigned int, pkrtz(b.x, b.y));
        hp.w = __builtin_bit_cast(unsigned int, pkrtz(b.z, b.w));
        *(uint4*)(void*)(h_lds + et * HROW + p * 8) = hp;
    }

    const int r16 = lane & 15;
    const int g   = lane >> 4;
    const int wbase = wave * 16;
    const int eg = ebase + wbase + r16;

    // ef fragment (independent of LDS; overlaps staging latency)
    const float* efp = efeat + eg * 16 + (g & 1) * 8;
    float4 e0 = *(const float4*)efp;
    float4 e1 = *(const float4*)(efp + 4);
    f16x2 ef2[4] = { pkrtz(e0.x, e0.y), pkrtz(e0.z, e0.w),
                     pkrtz(e1.x, e1.y), pkrtz(e1.z, e1.w) };

    __syncthreads();   // drains global_load_lds + ds_writes

    // h row -> regs; per-s broadcast half2 of h[2s + (g>>1)]
    unsigned int hbc[16];
    {
        const uint4* hrow = (const uint4*)(void*)(h_lds + (wbase + r16) * HROW);
        unsigned int hw[16];
        #pragma unroll
        for (int q = 0; q < 4; ++q) {
            uint4 v = hrow[q];
            hw[q*4+0] = v.x; hw[q*4+1] = v.y; hw[q*4+2] = v.z; hw[q*4+3] = v.w;
        }
        const bool hi = (g >> 1) & 1;
        #pragma unroll
        for (int s = 0; s < 16; ++s) {
            unsigned int x = hi ? (hw[s] >> 16) : (hw[s] & 0xffffu);
            hbc[s] = x | (x << 16);
        }
    }

    const _Float16* brow0 = (const _Float16*)wct_lds + r16 * WCT_ROW;
    const _Float16* brow1 = (const _Float16*)wct_lds + (16 + r16) * WCT_ROW;

    f32x4 acc0 = {0.f, 0.f, 0.f, 0.f};
    f32x4 acc1 = {0.f, 0.f, 0.f, 0.f};

    // X[e,c] = h[i]*ef[kk], c = 32s + 8g + j  =>  i = 2s+(g>>1), kk = (g&1)*8+j
    #pragma unroll
    for (int s = 0; s < 16; ++s) {
        const int koff = s * 32 + g * 8;
        f16x8 b0 = *(const f16x8*)(brow0 + koff);
        f16x8 b1 = *(const f16x8*)(brow1 + koff);
        f16x2 hb = __builtin_bit_cast(f16x2, hbc[s]);
        f16x2 p0 = hb * ef2[0], p1 = hb * ef2[1], p2 = hb * ef2[2], p3 = hb * ef2[3];
        f16x4 lo  = __builtin_shufflevector(p0, p1, 0, 1, 2, 3);
        f16x4 hi4 = __builtin_shufflevector(p2, p3, 0, 1, 2, 3);
        f16x8 af  = __builtin_shufflevector(lo, hi4, 0, 1, 2, 3, 4, 5, 6, 7);
        acc0 = __builtin_amdgcn_mfma_f32_16x16x32_f16(af, b0, acc0, 0, 0, 0);
        acc1 = __builtin_amdgcn_mfma_f32_16x16x32_f16(af, b1, acc1, 0, 0, 0);
    }
    {   // bias-extension k-step: X[e, 512+i] = h[i]
        const int koff = 512 + g * 8;
        f16x8 b0 = *(const f16x8*)(brow0 + koff);
        f16x8 b1 = *(const f16x8*)(brow1 + koff);
        f16x8 af = *(const f16x8*)(void*)((const _Float16*)h_lds + (wbase + r16) * HROW + g * 8);
        acc0 = __builtin_amdgcn_mfma_f32_16x16x32_f16(af, b0, acc0, 0, 0, 0);
        acc1 = __builtin_amdgcn_mfma_f32_16x16x32_f16(af, b1, acc1, 0, 0, 0);
    }

    // D (m89): row = g*4+r (edge in wave tile), col = r16 -> dtile[64][36]
    {
        const int browD = wbase + g * 4;
        #pragma unroll
        for (int r = 0; r < 4; ++r) {
            dtile[(browD + r) * DROW + r16]      = acc0[r];
            dtile[(browD + r) * DROW + 16 + r16] = acc1[r];
        }
    }
    __syncthreads();

    // Coalesced msg store: thread t -> edge et, 8 consecutive channels (32B)
    {
        const int et = t >> 2, q = t & 3;
        const float* drow = dtile + et * DROW + q * 8;
        float4 v0 = *(const float4*)(drow);
        float4 v1 = *(const float4*)(drow + 4);
        float* mp = msg + (ebase + et) * 32 + q * 8;
        *(float4*)(mp)     = v0;
        *(float4*)(mp + 4) = v1;
    }
}

// ---- D3: pull — one thread per node walks its chain, fused mean+bias ----
__global__ __launch_bounds__(256) void pull_kernel(
    const float* __restrict__ msg, const unsigned* __restrict__ head,
    const unsigned* __restrict__ next, const float* __restrict__ bias,
    float* __restrict__ out) {

    int n = blockIdx.x * 256 + threadIdx.x;
    if (n >= NNODES) return;

    float4 s0 = {0,0,0,0}, s1 = {0,0,0,0}, s2 = {0,0,0,0}, s3 = {0,0,0,0};
    float4 s4 = {0,0,0,0}, s5 = {0,0,0,0}, s6 = {0,0,0,0}, s7 = {0,0,0,0};
    float degf = 0.0f;

    unsigned e = head[n];
    while (e != 0xFFFFFFFFu) {
        const float4* mp = (const float4*)(msg + e * 32);
        float4 m0 = mp[0], m1 = mp[1], m2 = mp[2], m3 = mp[3];
        float4 m4 = mp[4], m5 = mp[5], m6 = mp[6], m7 = mp[7];
        s0.x+=m0.x; s0.y+=m0.y; s0.z+=m0.z; s0.w+=m0.w;
        s1.x+=m1.x; s1.y+=m1.y; s1.z+=m1.z; s1.w+=m1.w;
        s2.x+=m2.x; s2.y+=m2.y; s2.z+=m2.z; s2.w+=m2.w;
        s3.x+=m3.x; s3.y+=m3.y; s3.z+=m3.z; s3.w+=m3.w;
        s4.x+=m4.x; s4.y+=m4.y; s4.z+=m4.z; s4.w+=m4.w;
        s5.x+=m5.x; s5.y+=m5.y; s5.z+=m5.z; s5.w+=m5.w;
        s6.x+=m6.x; s6.y+=m6.y; s6.z+=m6.z; s6.w+=m6.w;
        s7.x+=m7.x; s7.y+=m7.y; s7.z+=m7.z; s7.w+=m7.w;
        degf += 1.0f;
        e = next[e];
    }

    float inv = 1.0f / fmaxf(degf, 1.0f);
    const float4* bp = (const float4*)bias;
    float4 o;
    float* op = out + n * 32;
    #define EMIT(S, Q) \
        o.x = S.x*inv + bp[Q].x; o.y = S.y*inv + bp[Q].y; \
        o.z = S.z*inv + bp[Q].z; o.w = S.w*inv + bp[Q].w; \
        *(float4*)(op + Q*4) = o;
    EMIT(s0,0) EMIT(s1,1) EMIT(s2,2) EMIT(s3,3)
    EMIT(s4,4) EMIT(s5,5) EMIT(s6,6) EMIT(s7,7)
    #undef EMIT
}

extern "C" void kernel_launch(void* const* d_in, const int* in_sizes, int n_in,
                              void* d_out, int out_size, void* d_ws, size_t ws_size,
                              hipStream_t stream) {
    const float* feat   = (const float*)d_in[0];
    const float* efeat  = (const float*)d_in[1];
    const int*   src    = (const int*)d_in[2];
    const int*   dst    = (const int*)d_in[3];
    const float* W_edge = (const float*)d_in[4];
    const float* b_edge = (const float*)d_in[5];
    const float* bias   = (const float*)d_in[6];

    char* ws = (char*)d_ws;
    float*    msg  = (float*)(ws + MSG_OFF);
    unsigned* head = (unsigned*)(ws + HEAD_OFF);
    unsigned* next = (unsigned*)(ws + NEXT_OFF);
    _Float16* wct  = (_Float16*)(ws + WCT_OFF);
    float*    out  = (float*)d_out;

    init_kernel<<<WCT_BLKS + (NNODES + 255) / 256, 256, 0, stream>>>(
        W_edge, b_edge, wct, head);
    work_kernel<<<NTILES + CHAIN_BLKS, 256, 0, stream>>>(
        feat, efeat, src, dst, wct, msg, head, next);
    pull_kernel<<<(NNODES + 255) / 256, 256, 0, stream>>>(
        msg, head, next, bias, out);
}